// Round 11
// baseline (978.890 us; speedup 1.0000x reference)
//
#include <hip/hip_runtime.h>

// OctreeConv: out[N,64] = sum_k gather_k(input)[N,32] @ W[k][32,64]
// Round 10: chunked pass sweep for L2 locality. R9 proved the limiter is
// the random-64B L2-miss service rate (~3 TB/s). Split input into 4 x 4MB
// chunks (= one XCD L2); pass loop OUTERMOST; per pass only rows with
// idx>>16==p are gathered (exec-masked; other rows contribute zero, and
// MFMA accumulation across passes reconstructs the full sum). 256 blocks
// = 1/CU in one batch -> loose pass-lockstep -> chunk-resident gathers.
// voff table precomputed transposed in d_ws; out/voff accesses nontemporal.

typedef float  f32x4  __attribute__((ext_vector_type(4)));
typedef __bf16 bf16x8 __attribute__((ext_vector_type(8)));
typedef int    i32x4  __attribute__((ext_vector_type(4)));
typedef ushort u16x4  __attribute__((ext_vector_type(4)));
typedef ushort u16x8  __attribute__((ext_vector_type(8)));

#define NN 262144
#define CI 32
#define CO 64
#define KK 27
#define PASSES 4
#define CHUNK_SH 22           // voff>>22 == idx>>16 == chunk id (64K rows/chunk)
#define THREADS 1024
#define TILE_T 4              // 4 A-tiles x 16 waves = 1024 octants/block
#define OCT_PER_BLOCK 1024    // grid = 256 = 1 block/CU (single batch)

__device__ __forceinline__ ushort f2bf_rne(float f) {
  union { float f; unsigned u; } v; v.f = f;
  unsigned u = v.u;
  u += 0x7FFFu + ((u >> 16) & 1u);
  return (ushort)(u >> 16);
}

// fp32 -> bf16 pre-pass (zero row at NN kept for the fallback path).
__global__ __launch_bounds__(256) void cvt_input_kernel(
    const float* __restrict__ in, ushort* __restrict__ out) {
  const int bid = blockIdx.x;
  if (bid == (NN * CI) / 1024) {
    if (threadIdx.x < 8) {
      u16x4 z = {0, 0, 0, 0};
      *(u16x4*)(out + (size_t)NN * CI + threadIdx.x * 4) = z;
    }
    return;
  }
  const int i = (bid * 256 + threadIdx.x) * 4;
  f32x4 v = *(const f32x4*)(in + i);
  u16x4 o;
  o[0] = f2bf_rne(v[0]); o[1] = f2bf_rne(v[1]);
  o[2] = f2bf_rne(v[2]); o[3] = f2bf_rne(v[3]);
  *(u16x4*)(out + i) = o;
}

// Transpose+encode neighbor table: voffT[k][n] = rowbyteoff(idx or sentinel).
// Invalid -> NN<<6: chunk id 4, never matches any pass -> contributes zero.
__global__ __launch_bounds__(256) void prep_voff_kernel(
    const int* __restrict__ neigh, uint32_t* __restrict__ voffT) {
  const int i = blockIdx.x * 256 + threadIdx.x;   // flat [N*K3), coalesced read
  if (i >= NN * KK) return;
  const int n = i / KK;
  const int k = i - n * KK;
  const int idx = neigh[i];
  voffT[(size_t)k * NN + n] = ((uint32_t)(idx < 0 ? NN : idx)) << 6;
}

__global__ __launch_bounds__(THREADS, 4) void octconv_chunked(
    const ushort* __restrict__ input,    // bf16 [NN+1][32] in d_ws
    const uint32_t* __restrict__ voffT,  // [27][NN] row byte-offsets in d_ws
    const float* __restrict__ weights,   // [27][32][64] fp32
    float* __restrict__ out)             // [N][64]
{
  __shared__ ushort w_lds[KK * 4 * CO * 8];   // 110,592 B (R5 layout, 0-conflict)

  for (int i = threadIdx.x; i < KK * 4 * CO; i += THREADS) {
    const int k = i >> 8;
    const int g = (i >> 6) & 3;
    const int o = i & 63;
    const float* wp = weights + ((size_t)k * CI + g * 8) * CO + o;
    u16x8 w;
#pragma unroll
    for (int j = 0; j < 8; ++j) w[j] = f2bf_rne(wp[j * CO]);
    *(u16x8*)&w_lds[i * 8] = w;
  }

  const int lane = threadIdx.x & 63;
  const int wave = threadIdx.x >> 6;
  const int g    = lane >> 4;
  const int r16  = lane & 15;
  const int oct_base = blockIdx.x * OCT_PER_BLOCK + wave * (16 * TILE_T);

  __syncthreads();

  f32x4 acc[TILE_T][4];
#pragma unroll
  for (int t = 0; t < TILE_T; ++t)
#pragma unroll
    for (int b = 0; b < 4; ++b) acc[t][b] = (f32x4){0.f, 0.f, 0.f, 0.f};

  const char* __restrict__ ibase = (const char*)input;
  const ushort* __restrict__ wfrag = &w_lds[g * (CO * 8) + r16 * 8];
  const uint32_t goff = g * 16;

  for (int p = 0; p < PASSES; ++p) {
#pragma unroll
    for (int k = 0; k < KK; ++k) {
      // per-tap row offsets for this lane's 4 tile-rows (streaming, NT)
      uint32_t vo[TILE_T];
#pragma unroll
      for (int t = 0; t < TILE_T; ++t)
        vo[t] = __builtin_nontemporal_load(
            &voffT[(size_t)k * NN + oct_base + t * 16 + r16]);

      // chunk-masked gathers: only rows resident in chunk p
      i32x4 av[TILE_T];
#pragma unroll
      for (int t = 0; t < TILE_T; ++t) {
        av[t] = (i32x4){0, 0, 0, 0};
        if ((vo[t] >> CHUNK_SH) == (uint32_t)p)
          av[t] = *(const i32x4*)(ibase + vo[t] + goff);
      }

#pragma unroll
      for (int t = 0; t < TILE_T; ++t) {
        const bf16x8 a = __builtin_bit_cast(bf16x8, av[t]);
#pragma unroll
        for (int b = 0; b < 4; ++b) {
          const bf16x8 bf = *(const bf16x8*)(wfrag + k * 2048 + b * 128);
          acc[t][b] = __builtin_amdgcn_mfma_f32_16x16x32_bf16(a, bf, acc[t][b], 0, 0, 0);
        }
      }
    }
  }

  // C/D layout: col = lane&15, row = (lane>>4)*4 + reg. NT stores keep L2
  // free for input chunks.
#pragma unroll
  for (int t = 0; t < TILE_T; ++t) {
    float* __restrict__ obase =
        out + (size_t)(oct_base + t * 16 + g * 4) * CO + r16;
#pragma unroll
    for (int rr = 0; rr < 4; ++rr)
#pragma unroll
      for (int b = 0; b < 4; ++b)
        __builtin_nontemporal_store(acc[t][b][rr], &obase[rr * CO + 16 * b]);
  }
}

// ---------- fallback 1: R5/R9 flat-gather kernel (passed, 106us) ----------
#define FB_OCT_PER_BLOCK 256
#define FB_PF 8
__global__ __launch_bounds__(THREADS, 4) void octconv_flat(
    const ushort* __restrict__ input, const float* __restrict__ weights,
    const int* __restrict__ neigh, float* __restrict__ out)
{
  __shared__ ushort w_lds[KK * 4 * CO * 8];
  for (int i = threadIdx.x; i < KK * 4 * CO; i += THREADS) {
    const int k = i >> 8;
    const int g = (i >> 6) & 3;
    const int o = i & 63;
    const float* wp = weights + ((size_t)k * CI + g * 8) * CO + o;
    u16x8 w;
#pragma unroll
    for (int j = 0; j < 8; ++j) w[j] = f2bf_rne(wp[j * CO]);
    *(u16x8*)&w_lds[i * 8] = w;
  }
  const int lane = threadIdx.x & 63;
  const int wave = threadIdx.x >> 6;
  const int g = lane >> 4, r16 = lane & 15;
  const int oct_base = blockIdx.x * FB_OCT_PER_BLOCK + wave * 16;
  uint32_t voff[KK];
  {
    const int* __restrict__ nrow = neigh + (size_t)(oct_base + r16) * KK;
#pragma unroll
    for (int k = 0; k < KK; ++k) {
      const int idx = nrow[k];
      voff[k] = ((uint32_t)(idx < 0 ? NN : idx) << 6) + g * 16;
    }
  }
  __syncthreads();
  f32x4 acc[4];
#pragma unroll
  for (int b = 0; b < 4; ++b) acc[b] = (f32x4){0.f, 0.f, 0.f, 0.f};
  const char* __restrict__ ibase = (const char*)input;
  const ushort* __restrict__ wfrag = &w_lds[g * (CO * 8) + r16 * 8];
  i32x4 abuf[FB_PF];
#pragma unroll
  for (int k = 0; k < FB_PF; ++k) abuf[k] = *(const i32x4*)(ibase + voff[k]);
#pragma unroll
  for (int k = 0; k < KK; ++k) {
    const bf16x8 a = __builtin_bit_cast(bf16x8, abuf[k % FB_PF]);
#pragma unroll
    for (int b = 0; b < 4; ++b) {
      const bf16x8 bf = *(const bf16x8*)(wfrag + k * 2048 + b * 128);
      acc[b] = __builtin_amdgcn_mfma_f32_16x16x32_bf16(a, bf, acc[b], 0, 0, 0);
    }
    if (k + FB_PF < KK) abuf[k % FB_PF] = *(const i32x4*)(ibase + voff[k + FB_PF]);
  }
  float* __restrict__ obase = out + (size_t)(oct_base + g * 4) * CO + r16;
#pragma unroll
  for (int rr = 0; rr < 4; ++rr)
#pragma unroll
    for (int b = 0; b < 4; ++b) obase[rr * CO + 16 * b] = acc[b][rr];
}

// ---------- fallback 2: fp32 gather + inline cvt (tiny ws) ----------
__global__ __launch_bounds__(THREADS, 4) void octconv_kernel_f32(
    const float* __restrict__ input, const float* __restrict__ weights,
    const int* __restrict__ neigh, float* __restrict__ out)
{
  __shared__ ushort w_lds[KK * 4 * CO * 8];
  for (int i = threadIdx.x; i < KK * 4 * CO; i += THREADS) {
    const int k = i >> 8;
    const int g = (i >> 6) & 3;
    const int o = i & 63;
    const float* wp = weights + ((size_t)k * CI + g * 8) * CO + o;
    u16x8 w;
#pragma unroll
    for (int j = 0; j < 8; ++j) w[j] = f2bf_rne(wp[j * CO]);
    *(u16x8*)&w_lds[i * 8] = w;
  }
  const int lane = threadIdx.x & 63;
  const int wave = threadIdx.x >> 6;
  const int g = lane >> 4, r16 = lane & 15;
  const int oct_base = blockIdx.x * FB_OCT_PER_BLOCK + wave * 16;
  const int* __restrict__ nrow = neigh + (size_t)(oct_base + r16) * KK;
  __syncthreads();
  f32x4 acc[4];
#pragma unroll
  for (int b = 0; b < 4; ++b) acc[b] = (f32x4){0.f, 0.f, 0.f, 0.f};
#pragma unroll
  for (int k = 0; k < KK; ++k) {
    const int idx = nrow[k];
    const float* ip = input + (size_t)(idx < 0 ? 0 : idx) * CI + g * 8;
    f32x4 v0 = *(const f32x4*)ip, v1 = *(const f32x4*)(ip + 4);
    if (idx < 0) { v0 = (f32x4){0,0,0,0}; v1 = (f32x4){0,0,0,0}; }
    bf16x8 a;
    a[0]=(__bf16)v0[0]; a[1]=(__bf16)v0[1]; a[2]=(__bf16)v0[2]; a[3]=(__bf16)v0[3];
    a[4]=(__bf16)v1[0]; a[5]=(__bf16)v1[1]; a[6]=(__bf16)v1[2]; a[7]=(__bf16)v1[3];
    const ushort* wk = &w_lds[(k * 4 + g) * (CO * 8) + r16 * 8];
#pragma unroll
    for (int b = 0; b < 4; ++b) {
      const bf16x8 bf = *(const bf16x8*)(wk + b * 128);
      acc[b] = __builtin_amdgcn_mfma_f32_16x16x32_bf16(a, bf, acc[b], 0, 0, 0);
    }
  }
  float* obase = out + (size_t)(oct_base + g * 4) * CO + r16;
#pragma unroll
  for (int rr = 0; rr < 4; ++rr)
#pragma unroll
    for (int b = 0; b < 4; ++b) obase[rr * CO + 16 * b] = acc[b][rr];
}

extern "C" void kernel_launch(void* const* d_in, const int* in_sizes, int n_in,
                              void* d_out, int out_size, void* d_ws, size_t ws_size,
                              hipStream_t stream) {
  const float* input   = (const float*)d_in[0];
  const float* weights = (const float*)d_in[1];
  const int*   neigh   = (const int*)d_in[2];
  float*       out     = (float*)d_out;

  const size_t bf16_bytes = ((size_t)NN + 1) * CI * sizeof(ushort);   // 16,777,280
  const size_t voff_off   = (bf16_bytes + 255) & ~(size_t)255;        // 16,777,472
  const size_t voff_bytes = (size_t)KK * NN * sizeof(uint32_t);       // 28,311,552
  const size_t need_chunk = voff_off + voff_bytes;                    // ~45.1 MB

  if (ws_size >= need_chunk) {
    ushort*   in_bf16 = (ushort*)d_ws;
    uint32_t* voffT   = (uint32_t*)((char*)d_ws + voff_off);
    cvt_input_kernel<<<dim3((NN * CI) / 1024 + 1), 256, 0, stream>>>(input, in_bf16);
    prep_voff_kernel<<<dim3((NN * KK + 255) / 256), 256, 0, stream>>>(neigh, voffT);
    octconv_chunked<<<dim3(NN / OCT_PER_BLOCK), THREADS, 0, stream>>>(
        in_bf16, voffT, weights, out);
  } else if (ws_size >= bf16_bytes) {
    ushort* in_bf16 = (ushort*)d_ws;
    cvt_input_kernel<<<dim3((NN * CI) / 1024 + 1), 256, 0, stream>>>(input, in_bf16);
    octconv_flat<<<dim3(NN / FB_OCT_PER_BLOCK), THREADS, 0, stream>>>(
        in_bf16, weights, neigh, out);
  } else {
    octconv_kernel_f32<<<dim3(NN / FB_OCT_PER_BLOCK), THREADS, 0, stream>>>(
        input, weights, neigh, out);
  }
}

// Round 12
// 636.307 us; speedup vs baseline: 1.5384x; 1.5384x over previous
//
#include <hip/hip_runtime.h>

// OctreeConv: out[N,64] = sum_k gather_k(input)[N,32] @ W[k][32,64]
// Round 11: R10's chunked pass sweep + REAL lockstep. R10 failed because
// blocks drifted across passes (no grid sync) -> each XCD L2 held a mix of
// chunks -> FETCH 1.84GB. Fix: software grid barrier between passes
// (monotonic counter in d_ws, zeroed by prep kernel; 256 blocks = 1/CU,
// all co-resident, so spinning is safe; barrier is pacing-only -- numeric
// correctness never depends on it).

typedef float  f32x4  __attribute__((ext_vector_type(4)));
typedef __bf16 bf16x8 __attribute__((ext_vector_type(8)));
typedef int    i32x4  __attribute__((ext_vector_type(4)));
typedef ushort u16x4  __attribute__((ext_vector_type(4)));
typedef ushort u16x8  __attribute__((ext_vector_type(8)));

#define NN 262144
#define CI 32
#define CO 64
#define KK 27
#define PASSES 4
#define CHUNK_SH 22           // voff>>22 == idx>>16 == chunk id (64K rows = 4MB)
#define THREADS 1024
#define TILE_T 4
#define OCT_PER_BLOCK 1024    // grid = 256 = 1 block/CU, all co-resident

__device__ __forceinline__ ushort f2bf_rne(float f) {
  union { float f; unsigned u; } v; v.f = f;
  unsigned u = v.u;
  u += 0x7FFFu + ((u >> 16) & 1u);
  return (ushort)(u >> 16);
}

__global__ __launch_bounds__(256) void cvt_input_kernel(
    const float* __restrict__ in, ushort* __restrict__ out) {
  const int bid = blockIdx.x;
  if (bid == (NN * CI) / 1024) {
    if (threadIdx.x < 8) {
      u16x4 z = {0, 0, 0, 0};
      *(u16x4*)(out + (size_t)NN * CI + threadIdx.x * 4) = z;
    }
    return;
  }
  const int i = (bid * 256 + threadIdx.x) * 4;
  f32x4 v = *(const f32x4*)(in + i);
  u16x4 o;
  o[0] = f2bf_rne(v[0]); o[1] = f2bf_rne(v[1]);
  o[2] = f2bf_rne(v[2]); o[3] = f2bf_rne(v[3]);
  *(u16x4*)(out + i) = o;
}

// Transpose+encode neighbor table; also zero the pacing-barrier counter
// (stream-ordered before the conv kernel every launch/replay).
__global__ __launch_bounds__(256) void prep_voff_kernel(
    const int* __restrict__ neigh, uint32_t* __restrict__ voffT,
    int* __restrict__ bar) {
  const int i = blockIdx.x * 256 + threadIdx.x;
  if (i == 0) bar[0] = 0;
  if (i >= NN * KK) return;
  const int n = i / KK;
  const int k = i - n * KK;
  const int idx = neigh[i];
  voffT[(size_t)k * NN + n] = ((uint32_t)(idx < 0 ? NN : idx)) << 6;
}

// Pacing barrier: monotonic counter, target = gridDim.x * phase.
// Correctness does not depend on it (gathers are read-only; acc is local).
__device__ __forceinline__ void pace_barrier(int* bar, int target) {
  __syncthreads();
  if (threadIdx.x == 0) {
    atomicAdd(bar, 1);
    while (__hip_atomic_load(bar, __ATOMIC_RELAXED,
                             __HIP_MEMORY_SCOPE_AGENT) < target) {
      __builtin_amdgcn_s_sleep(8);
    }
  }
  __syncthreads();
}

__global__ __launch_bounds__(THREADS, 4) void octconv_chunked(
    const ushort* __restrict__ input,    // bf16 [NN+1][32] in d_ws
    const uint32_t* __restrict__ voffT,  // [27][NN] row byte-offsets in d_ws
    const float* __restrict__ weights,   // [27][32][64] fp32
    float* __restrict__ out,             // [N][64]
    int* __restrict__ bar)               // pacing counter in d_ws
{
  __shared__ ushort w_lds[KK * 4 * CO * 8];   // 110,592 B (0-conflict layout)

  for (int i = threadIdx.x; i < KK * 4 * CO; i += THREADS) {
    const int k = i >> 8;
    const int g = (i >> 6) & 3;
    const int o = i & 63;
    const float* wp = weights + ((size_t)k * CI + g * 8) * CO + o;
    u16x8 w;
#pragma unroll
    for (int j = 0; j < 8; ++j) w[j] = f2bf_rne(wp[j * CO]);
    *(u16x8*)&w_lds[i * 8] = w;
  }

  const int lane = threadIdx.x & 63;
  const int wave = threadIdx.x >> 6;
  const int g    = lane >> 4;
  const int r16  = lane & 15;
  const int oct_base = blockIdx.x * OCT_PER_BLOCK + wave * (16 * TILE_T);

  __syncthreads();

  f32x4 acc[TILE_T][4];
#pragma unroll
  for (int t = 0; t < TILE_T; ++t)
#pragma unroll
    for (int b = 0; b < 4; ++b) acc[t][b] = (f32x4){0.f, 0.f, 0.f, 0.f};

  const char* __restrict__ ibase = (const char*)input;
  const ushort* __restrict__ wfrag = &w_lds[g * (CO * 8) + r16 * 8];
  const uint32_t goff = g * 16;

  for (int p = 0; p < PASSES; ++p) {
    if (p) pace_barrier(bar, (int)gridDim.x * p);   // lockstep pass sweep

#pragma unroll
    for (int k = 0; k < KK; ++k) {
      // per-tap row offsets (NT streaming: don't evict the resident chunk)
      uint32_t vo[TILE_T];
#pragma unroll
      for (int t = 0; t < TILE_T; ++t)
        vo[t] = __builtin_nontemporal_load(
            &voffT[(size_t)k * NN + oct_base + t * 16 + r16]);

      // chunk-masked gathers: only rows resident in chunk p (L2-hot)
      i32x4 av[TILE_T];
#pragma unroll
      for (int t = 0; t < TILE_T; ++t) {
        av[t] = (i32x4){0, 0, 0, 0};
        if ((vo[t] >> CHUNK_SH) == (uint32_t)p)
          av[t] = *(const i32x4*)(ibase + vo[t] + goff);
      }

#pragma unroll
      for (int t = 0; t < TILE_T; ++t) {
        const bf16x8 a = __builtin_bit_cast(bf16x8, av[t]);
#pragma unroll
        for (int b = 0; b < 4; ++b) {
          const bf16x8 bf = *(const bf16x8*)(wfrag + k * 2048 + b * 128);
          acc[t][b] = __builtin_amdgcn_mfma_f32_16x16x32_bf16(a, bf, acc[t][b], 0, 0, 0);
        }
      }
    }
  }

  // C/D layout: col = lane&15, row = (lane>>4)*4 + reg; NT stores.
#pragma unroll
  for (int t = 0; t < TILE_T; ++t) {
    float* __restrict__ obase =
        out + (size_t)(oct_base + t * 16 + g * 4) * CO + r16;
#pragma unroll
    for (int rr = 0; rr < 4; ++rr)
#pragma unroll
      for (int b = 0; b < 4; ++b)
        __builtin_nontemporal_store(acc[t][b][rr], &obase[rr * CO + 16 * b]);
  }
}

// ---------- fallback 1: R9 flat-gather kernel (passed, 106us) ----------
#define FB_OCT_PER_BLOCK 256
#define FB_PF 8
__global__ __launch_bounds__(THREADS, 4) void octconv_flat(
    const ushort* __restrict__ input, const float* __restrict__ weights,
    const int* __restrict__ neigh, float* __restrict__ out)
{
  __shared__ ushort w_lds[KK * 4 * CO * 8];
  for (int i = threadIdx.x; i < KK * 4 * CO; i += THREADS) {
    const int k = i >> 8;
    const int g = (i >> 6) & 3;
    const int o = i & 63;
    const float* wp = weights + ((size_t)k * CI + g * 8) * CO + o;
    u16x8 w;
#pragma unroll
    for (int j = 0; j < 8; ++j) w[j] = f2bf_rne(wp[j * CO]);
    *(u16x8*)&w_lds[i * 8] = w;
  }
  const int lane = threadIdx.x & 63;
  const int wave = threadIdx.x >> 6;
  const int g = lane >> 4, r16 = lane & 15;
  const int oct_base = blockIdx.x * FB_OCT_PER_BLOCK + wave * 16;
  uint32_t voff[KK];
  {
    const int* __restrict__ nrow = neigh + (size_t)(oct_base + r16) * KK;
#pragma unroll
    for (int k = 0; k < KK; ++k) {
      const int idx = nrow[k];
      voff[k] = ((uint32_t)(idx < 0 ? NN : idx) << 6) + g * 16;
    }
  }
  __syncthreads();
  f32x4 acc[4];
#pragma unroll
  for (int b = 0; b < 4; ++b) acc[b] = (f32x4){0.f, 0.f, 0.f, 0.f};
  const char* __restrict__ ibase = (const char*)input;
  const ushort* __restrict__ wfrag = &w_lds[g * (CO * 8) + r16 * 8];
  i32x4 abuf[FB_PF];
#pragma unroll
  for (int k = 0; k < FB_PF; ++k) abuf[k] = *(const i32x4*)(ibase + voff[k]);
#pragma unroll
  for (int k = 0; k < KK; ++k) {
    const bf16x8 a = __builtin_bit_cast(bf16x8, abuf[k % FB_PF]);
#pragma unroll
    for (int b = 0; b < 4; ++b) {
      const bf16x8 bf = *(const bf16x8*)(wfrag + k * 2048 + b * 128);
      acc[b] = __builtin_amdgcn_mfma_f32_16x16x32_bf16(a, bf, acc[b], 0, 0, 0);
    }
    if (k + FB_PF < KK) abuf[k % FB_PF] = *(const i32x4*)(ibase + voff[k + FB_PF]);
  }
  float* __restrict__ obase = out + (size_t)(oct_base + g * 4) * CO + r16;
#pragma unroll
  for (int rr = 0; rr < 4; ++rr)
#pragma unroll
    for (int b = 0; b < 4; ++b) obase[rr * CO + 16 * b] = acc[b][rr];
}

// ---------- fallback 2: fp32 gather + inline cvt (tiny ws) ----------
__global__ __launch_bounds__(THREADS, 4) void octconv_kernel_f32(
    const float* __restrict__ input, const float* __restrict__ weights,
    const int* __restrict__ neigh, float* __restrict__ out)
{
  __shared__ ushort w_lds[KK * 4 * CO * 8];
  for (int i = threadIdx.x; i < KK * 4 * CO; i += THREADS) {
    const int k = i >> 8;
    const int g = (i >> 6) & 3;
    const int o = i & 63;
    const float* wp = weights + ((size_t)k * CI + g * 8) * CO + o;
    u16x8 w;
#pragma unroll
    for (int j = 0; j < 8; ++j) w[j] = f2bf_rne(wp[j * CO]);
    *(u16x8*)&w_lds[i * 8] = w;
  }
  const int lane = threadIdx.x & 63;
  const int wave = threadIdx.x >> 6;
  const int g = lane >> 4, r16 = lane & 15;
  const int oct_base = blockIdx.x * FB_OCT_PER_BLOCK + wave * 16;
  const int* __restrict__ nrow = neigh + (size_t)(oct_base + r16) * KK;
  __syncthreads();
  f32x4 acc[4];
#pragma unroll
  for (int b = 0; b < 4; ++b) acc[b] = (f32x4){0.f, 0.f, 0.f, 0.f};
#pragma unroll
  for (int k = 0; k < KK; ++k) {
    const int idx = nrow[k];
    const float* ip = input + (size_t)(idx < 0 ? 0 : idx) * CI + g * 8;
    f32x4 v0 = *(const f32x4*)ip, v1 = *(const f32x4*)(ip + 4);
    if (idx < 0) { v0 = (f32x4){0,0,0,0}; v1 = (f32x4){0,0,0,0}; }
    bf16x8 a;
    a[0]=(__bf16)v0[0]; a[1]=(__bf16)v0[1]; a[2]=(__bf16)v0[2]; a[3]=(__bf16)v0[3];
    a[4]=(__bf16)v1[0]; a[5]=(__bf16)v1[1]; a[6]=(__bf16)v1[2]; a[7]=(__bf16)v1[3];
    const ushort* wk = &w_lds[(k * 4 + g) * (CO * 8) + r16 * 8];
#pragma unroll
    for (int b = 0; b < 4; ++b) {
      const bf16x8 bf = *(const bf16x8*)(wk + b * 128);
      acc[b] = __builtin_amdgcn_mfma_f32_16x16x32_bf16(a, bf, acc[b], 0, 0, 0);
    }
  }
  float* obase = out + (size_t)(oct_base + g * 4) * CO + r16;
#pragma unroll
  for (int rr = 0; rr < 4; ++rr)
#pragma unroll
    for (int b = 0; b < 4; ++b) obase[rr * CO + 16 * b] = acc[b][rr];
}

extern "C" void kernel_launch(void* const* d_in, const int* in_sizes, int n_in,
                              void* d_out, int out_size, void* d_ws, size_t ws_size,
                              hipStream_t stream) {
  const float* input   = (const float*)d_in[0];
  const float* weights = (const float*)d_in[1];
  const int*   neigh   = (const int*)d_in[2];
  float*       out     = (float*)d_out;

  const size_t bf16_bytes = ((size_t)NN + 1) * CI * sizeof(ushort);   // 16,777,280
  const size_t voff_off   = (bf16_bytes + 255) & ~(size_t)255;
  const size_t voff_bytes = (size_t)KK * NN * sizeof(uint32_t);       // 28,311,552
  const size_t bar_off    = (voff_off + voff_bytes + 255) & ~(size_t)255;
  const size_t need_chunk = bar_off + 256;                            // ~45.1 MB

  if (ws_size >= need_chunk) {
    ushort*   in_bf16 = (ushort*)d_ws;
    uint32_t* voffT   = (uint32_t*)((char*)d_ws + voff_off);
    int*      bar     = (int*)((char*)d_ws + bar_off);
    cvt_input_kernel<<<dim3((NN * CI) / 1024 + 1), 256, 0, stream>>>(input, in_bf16);
    prep_voff_kernel<<<dim3((NN * KK + 255) / 256), 256, 0, stream>>>(neigh, voffT, bar);
    octconv_chunked<<<dim3(NN / OCT_PER_BLOCK), THREADS, 0, stream>>>(
        in_bf16, voffT, weights, out, bar);
  } else if (ws_size >= bf16_bytes) {
    ushort* in_bf16 = (ushort*)d_ws;
    cvt_input_kernel<<<dim3((NN * CI) / 1024 + 1), 256, 0, stream>>>(input, in_bf16);
    octconv_flat<<<dim3(NN / FB_OCT_PER_BLOCK), THREADS, 0, stream>>>(
        in_bf16, weights, neigh, out);
  } else {
    octconv_kernel_f32<<<dim3(NN / FB_OCT_PER_BLOCK), THREADS, 0, stream>>>(
        input, weights, neigh, out);
  }
}

// Round 14
// 114.167 us; speedup vs baseline: 8.5742x; 5.5735x over previous
//
#include <hip/hip_runtime.h>

// OctreeConv: out[N,64] = sum_k gather_k(input)[N,32] @ W[k][32,64]
// Round 13: byte-exact resubmit of the R5 kernel (passed, conv=106us,
// post-timing revalidated). R12 (same structure, PF=8) diverged AFTER
// graph replays despite deterministic dataflow -- unexplained; reverting
// to the exact proven source (PF=12) to disambiguate flake vs codegen.
// Evidence for roofline (if this passes): gather pinned at ~3.5 TB/s
// random-64B service rate across R1/R2/R4/R5/R6/R9; chunked passes
// (R10/R11) raised FETCH 3-9x; neigh is uniform-random so per-XCD L2
// hit is capped ~25% (measured 20%). Floor arithmetic ~100us vs 106us.

typedef float  f32x4  __attribute__((ext_vector_type(4)));
typedef __bf16 bf16x8 __attribute__((ext_vector_type(8)));
typedef int    i32x4  __attribute__((ext_vector_type(4)));
typedef ushort u16x4  __attribute__((ext_vector_type(4)));
typedef ushort u16x8  __attribute__((ext_vector_type(8)));

#define NN 262144
#define CI 32
#define CO 64
#define KK 27
#define THREADS 1024
#define PF 12                 // gather prefetch depth (R5-exact)
#define OCT_PER_BLOCK 256     // 16 waves x 16 octants

__device__ __forceinline__ ushort f2bf_rne(float f) {
  union { float f; unsigned u; } v; v.f = f;
  unsigned u = v.u;
  u += 0x7FFFu + ((u >> 16) & 1u);
  return (ushort)(u >> 16);
}

// fp32 -> bf16 pre-pass; last block writes a zero row at index NN
// (gather target for invalid neighbors).
__global__ __launch_bounds__(256) void cvt_input_kernel(
    const float* __restrict__ in, ushort* __restrict__ out) {
  const int bid = blockIdx.x;
  if (bid == (NN * CI) / 1024) {
    if (threadIdx.x < 8) {
      u16x4 z = {0, 0, 0, 0};
      *(u16x4*)(out + (size_t)NN * CI + threadIdx.x * 4) = z;
    }
    return;
  }
  const int i = (bid * 256 + threadIdx.x) * 4;
  f32x4 v = *(const f32x4*)(in + i);
  u16x4 o;
  o[0] = f2bf_rne(v[0]); o[1] = f2bf_rne(v[1]);
  o[2] = f2bf_rne(v[2]); o[3] = f2bf_rne(v[3]);
  *(u16x4*)(out + i) = o;
}

__global__ __launch_bounds__(THREADS, 4) void octconv_kernel(
    const ushort* __restrict__ input,   // bf16 [NN+1][32] in d_ws (row NN = 0)
    const float* __restrict__ weights,  // [27][32][64] fp32
    const int*   __restrict__ neigh,    // [N][27]
    float*       __restrict__ out)      // [N][64]
{
  // Compact weights: [k][g][o] of 8-channel bf16 vectors, 16B each.
  // Fragment read: 16B at ((k*4+g)*64 + r16 + 16b)*16 -> bank=(o*4)%32, 2-way max.
  __shared__ ushort w_lds[KK * 4 * CO * 8];   // 110,592 B -> 16 waves/CU

  for (int i = threadIdx.x; i < KK * 4 * CO; i += THREADS) {
    const int k = i >> 8;
    const int g = (i >> 6) & 3;
    const int o = i & 63;
    const float* wp = weights + ((size_t)k * CI + g * 8) * CO + o;
    u16x8 w;
#pragma unroll
    for (int j = 0; j < 8; ++j) w[j] = f2bf_rne(wp[j * CO]);
    *(u16x8*)&w_lds[i * 8] = w;
  }

  const int lane = threadIdx.x & 63;
  const int wave = threadIdx.x >> 6;
  const int g    = lane >> 4;
  const int r16  = lane & 15;
  const int oct_base = blockIdx.x * OCT_PER_BLOCK + wave * 16;

  // Per-lane u32 byte offsets for all 27 gathers (invalid -> zero row NN).
  uint32_t voff[KK];
  {
    const int* __restrict__ nrow = neigh + (size_t)(oct_base + r16) * KK;
#pragma unroll
    for (int k = 0; k < KK; ++k) {
      const int idx = nrow[k];
      voff[k] = ((uint32_t)(idx < 0 ? NN : idx) << 6) + g * 16;
    }
  }

  __syncthreads();

  f32x4 acc[4];
#pragma unroll
  for (int b = 0; b < 4; ++b) acc[b] = (f32x4){0.f, 0.f, 0.f, 0.f};

  const char* __restrict__ ibase = (const char*)input;

  // 12-deep rotating gather pipeline (fully unrolled -> static indices).
  i32x4 abuf[PF];
#pragma unroll
  for (int k = 0; k < PF; ++k)
    abuf[k] = *(const i32x4*)(ibase + voff[k]);

#pragma unroll
  for (int k = 0; k < KK; ++k) {
    const bf16x8 a = __builtin_bit_cast(bf16x8, abuf[k % PF]);
    const ushort* __restrict__ wk = &w_lds[(k * 4 + g) * (CO * 8) + r16 * 8];
#pragma unroll
    for (int b = 0; b < 4; ++b) {
      const bf16x8 bf = *(const bf16x8*)(wk + b * 128);   // +16 outputs
      acc[b] = __builtin_amdgcn_mfma_f32_16x16x32_bf16(a, bf, acc[b], 0, 0, 0);
    }
    if (k + PF < KK)
      abuf[k % PF] = *(const i32x4*)(ibase + voff[k + PF]);
  }

  // C/D layout: col = lane&15, row = (lane>>4)*4 + reg
  float* __restrict__ obase = out + (size_t)(oct_base + g * 4) * CO + r16;
#pragma unroll
  for (int rr = 0; rr < 4; ++rr)
#pragma unroll
    for (int b = 0; b < 4; ++b)
      obase[rr * CO + 16 * b] = acc[b][rr];
}

// Fallback (ws too small for bf16 copy): fp32 gather + inline cvt, no pipeline.
__global__ __launch_bounds__(THREADS, 4) void octconv_kernel_f32(
    const float* __restrict__ input, const float* __restrict__ weights,
    const int* __restrict__ neigh, float* __restrict__ out)
{
  __shared__ ushort w_lds[KK * 4 * CO * 8];
  for (int i = threadIdx.x; i < KK * 4 * CO; i += THREADS) {
    const int k = i >> 8;
    const int g = (i >> 6) & 3;
    const int o = i & 63;
    const float* wp = weights + ((size_t)k * CI + g * 8) * CO + o;
    u16x8 w;
#pragma unroll
    for (int j = 0; j < 8; ++j) w[j] = f2bf_rne(wp[j * CO]);
    *(u16x8*)&w_lds[i * 8] = w;
  }
  const int lane = threadIdx.x & 63;
  const int wave = threadIdx.x >> 6;
  const int g = lane >> 4, r16 = lane & 15;
  const int oct_base = blockIdx.x * OCT_PER_BLOCK + wave * 16;
  const int* __restrict__ nrow = neigh + (size_t)(oct_base + r16) * KK;
  __syncthreads();
  f32x4 acc[4];
#pragma unroll
  for (int b = 0; b < 4; ++b) acc[b] = (f32x4){0.f, 0.f, 0.f, 0.f};
#pragma unroll
  for (int k = 0; k < KK; ++k) {
    const int idx = nrow[k];
    const float* ip = input + (size_t)(idx < 0 ? 0 : idx) * CI + g * 8;
    f32x4 v0 = *(const f32x4*)ip, v1 = *(const f32x4*)(ip + 4);
    if (idx < 0) { v0 = (f32x4){0,0,0,0}; v1 = (f32x4){0,0,0,0}; }
    bf16x8 a;
    a[0]=(__bf16)v0[0]; a[1]=(__bf16)v0[1]; a[2]=(__bf16)v0[2]; a[3]=(__bf16)v0[3];
    a[4]=(__bf16)v1[0]; a[5]=(__bf16)v1[1]; a[6]=(__bf16)v1[2]; a[7]=(__bf16)v1[3];
    const ushort* wk = &w_lds[(k * 4 + g) * (CO * 8) + r16 * 8];
#pragma unroll
    for (int b = 0; b < 4; ++b) {
      const bf16x8 bf = *(const bf16x8*)(wk + b * 128);
      acc[b] = __builtin_amdgcn_mfma_f32_16x16x32_bf16(a, bf, acc[b], 0, 0, 0);
    }
  }
  float* obase = out + (size_t)(oct_base + g * 4) * CO + r16;
#pragma unroll
  for (int rr = 0; rr < 4; ++rr)
#pragma unroll
    for (int b = 0; b < 4; ++b)
      acc[b][rr], obase[rr * CO + 16 * b] = acc[b][rr];
}

extern "C" void kernel_launch(void* const* d_in, const int* in_sizes, int n_in,
                              void* d_out, int out_size, void* d_ws, size_t ws_size,
                              hipStream_t stream) {
  const float* input   = (const float*)d_in[0];
  const float* weights = (const float*)d_in[1];
  const int*   neigh   = (const int*)d_in[2];
  float*       out     = (float*)d_out;

  const size_t bf16_bytes = ((size_t)NN + 1) * CI * sizeof(ushort);  // 16 MiB + row
  dim3 grid(NN / OCT_PER_BLOCK);   // 1024 blocks

  if (ws_size >= bf16_bytes) {
    ushort* in_bf16 = (ushort*)d_ws;
    cvt_input_kernel<<<dim3((NN * CI) / 1024 + 1), 256, 0, stream>>>(input, in_bf16);
    octconv_kernel<<<grid, THREADS, 0, stream>>>(in_bf16, weights, neigh, out);
  } else {
    octconv_kernel_f32<<<grid, THREADS, 0, stream>>>(input, weights, neigh, out);
  }
}